// Round 4
// baseline (344.232 us; speedup 1.0000x reference)
//
#include <hip/hip_runtime.h>

#define NB 4
#define QLEN 2048
#define KLEN 2048
#define QDIM 512
#define EMBED 1024
#define HEADS 16
#define HD 64

typedef __bf16 bf16x8 __attribute__((ext_vector_type(8)));
typedef float f32x2 __attribute__((ext_vector_type(2)));
typedef float f32x4 __attribute__((ext_vector_type(4)));
typedef float f32x16 __attribute__((ext_vector_type(16)));

#define CLOG 0.18033688011112042f   // 0.125 * log2(e), folded into Wq

// guaranteed-cheap exp2
__device__ __forceinline__ float fexp2(float x) {
#if __has_builtin(__builtin_amdgcn_exp2f)
    return __builtin_amdgcn_exp2f(x);
#else
    float r;
    asm("v_exp_f32 %0, %1\n\ts_nop 1" : "=v"(r) : "v"(x));
    return r;
#endif
}

#if __has_builtin(__builtin_amdgcn_sched_barrier)
#define SCHED_FENCE() __builtin_amdgcn_sched_barrier(0)
#else
#define SCHED_FENCE()
#endif

// async global->LDS 16B: dest = wave-uniform base + lane*16
__device__ __forceinline__ void dma16(const void* g, void* l) {
    __builtin_amdgcn_global_load_lds(
        (const __attribute__((address_space(1))) void*)g,
        (__attribute__((address_space(3))) void*)l, 16, 0, 0);
}

// ---------------------------------------------------------------------------
// prep: fused bf16 casts (q,k,v) + W transposes. 1D grid of 4608 blocks x 256.
// ---------------------------------------------------------------------------
__global__ __launch_bounds__(256) void prep(const float* __restrict__ q,
                                            const float* __restrict__ k,
                                            const float* __restrict__ v,
                                            const float* __restrict__ Wq,
                                            const float* __restrict__ Wk,
                                            const float* __restrict__ Wv,
                                            __bf16* __restrict__ qd,
                                            __bf16* __restrict__ kd,
                                            __bf16* __restrict__ vd,
                                            __bf16* __restrict__ WtQ,
                                            __bf16* __restrict__ WtK,
                                            __bf16* __restrict__ WtV) {
    __shared__ float tile[32][33];
    int b = blockIdx.x, tid = threadIdx.x;
    if (b < 3072) {
        const float* src; __bf16* dst; int cb;
        if (b < 2048)      { src = q; dst = qd; cb = b; }
        else if (b < 2560) { src = k; dst = kd; cb = b - 2048; }
        else               { src = v; dst = vd; cb = b - 2560; }
        int i = (cb * 256 + tid) * 8;
        float4 a0 = *(const float4*)&src[i];
        float4 a1 = *(const float4*)&src[i + 4];
        bf16x8 o;
        o[0] = (__bf16)a0.x; o[1] = (__bf16)a0.y; o[2] = (__bf16)a0.z; o[3] = (__bf16)a0.w;
        o[4] = (__bf16)a1.x; o[5] = (__bf16)a1.y; o[6] = (__bf16)a1.z; o[7] = (__bf16)a1.w;
        *(bf16x8*)&dst[i] = o;
    } else {
        int tb = b - 3072;
        int which = tb >> 9, r = tb & 511;
        const float* src = (which == 0) ? Wq : (which == 1) ? Wk : Wv;
        __bf16* dst = (which == 0) ? WtQ : (which == 1) ? WtK : WtV;
        float scale = (which == 0) ? CLOG : 1.0f;
        int e0 = (r & 31) * 32, c0 = (r >> 5) * 32;
        int tx = tid & 31, ty = tid >> 5;  // 32 x 8
        for (int i = 0; i < 4; i++)
            tile[ty + 8 * i][tx] = src[(c0 + ty + 8 * i) * EMBED + e0 + tx];
        __syncthreads();
        for (int i = 0; i < 4; i++)
            dst[(e0 + ty + 8 * i) * QDIM + c0 + tx] = (__bf16)(tile[tx][ty + 8 * i] * scale);
    }
}

// ---------------------------------------------------------------------------
// 128x128-tile GEMM body, double-buffered DMA staging, BK=32, 2x2 wave grid
// ---------------------------------------------------------------------------
__device__ __forceinline__ void gemm_compute(const __bf16* As, const __bf16* Bs,
                                             int wr, int wc, int r16, int qq,
                                             f32x4 (&acc)[4][4]) {
    bf16x8 af[4], bq[4];
#pragma unroll
    for (int i = 0; i < 4; i++)
        af[i] = *(const bf16x8*)&As[(wr * 64 + i * 16 + r16) * 32 + qq * 8];
#pragma unroll
    for (int j = 0; j < 4; j++)
        bq[j] = *(const bf16x8*)&Bs[(wc * 64 + j * 16 + r16) * 32 + qq * 8];
#pragma unroll
    for (int i = 0; i < 4; i++)
#pragma unroll
        for (int j = 0; j < 4; j++)
            acc[i][j] = __builtin_amdgcn_mfma_f32_16x16x32_bf16(af[i], bq[j], acc[i][j], 0, 0, 0);
}

__device__ __forceinline__ void gemm128(const __bf16* __restrict__ A,
                                        const __bf16* __restrict__ Bt,
                                        __bf16* As0, __bf16* As1,
                                        __bf16* Bs0, __bf16* Bs1,
                                        int row0, int col0, f32x4 (&acc)[4][4]) {
    int tid = threadIdx.x, wave = tid >> 6, lane = tid & 63;
    int r16 = lane & 15, qq = lane >> 4;
    int wr = wave >> 1, wc = wave & 1;
    const __bf16* agp1 = A + (size_t)(row0 + (tid >> 2)) * QDIM + (tid & 3) * 8;
    const __bf16* agp2 = A + (size_t)(row0 + 64 + (tid >> 2)) * QDIM + (tid & 3) * 8;
    const __bf16* bgp1 = Bt + (size_t)(col0 + (tid >> 2)) * QDIM + (tid & 3) * 8;
    const __bf16* bgp2 = Bt + (size_t)(col0 + 64 + (tid >> 2)) * QDIM + (tid & 3) * 8;
    __bf16 *a0a = &As0[wave * 512], *a0b = &As0[2048 + wave * 512];
    __bf16 *a1a = &As1[wave * 512], *a1b = &As1[2048 + wave * 512];
    __bf16 *b0a = &Bs0[wave * 512], *b0b = &Bs0[2048 + wave * 512];
    __bf16 *b1a = &Bs1[wave * 512], *b1b = &Bs1[2048 + wave * 512];

    // prologue: tile 0 -> buf0
    dma16(agp1, a0a); dma16(agp2, a0b);
    dma16(bgp1, b0a); dma16(bgp2, b0b);
    agp1 += 32; agp2 += 32; bgp1 += 32; bgp2 += 32;
    __syncthreads();

    for (int t = 0; t < 16; t += 2) {
        // prefetch tile t+1 -> buf1 (t+1 <= 15 always)
        dma16(agp1, a1a); dma16(agp2, a1b);
        dma16(bgp1, b1a); dma16(bgp2, b1b);
        agp1 += 32; agp2 += 32; bgp1 += 32; bgp2 += 32;
        SCHED_FENCE();
        gemm_compute(As0, Bs0, wr, wc, r16, qq, acc);
        __syncthreads();
        if (t + 2 < 16) {
            dma16(agp1, a0a); dma16(agp2, a0b);
            dma16(bgp1, b0a); dma16(bgp2, b0b);
            agp1 += 32; agp2 += 32; bgp1 += 32; bgp2 += 32;
        }
        SCHED_FENCE();
        gemm_compute(As1, Bs1, wr, wc, r16, qq, acc);
        __syncthreads();
    }
}

// ---------------------------------------------------------------------------
// fused projections: bid<512 -> q ; <640 -> k ; else -> vT
// mode 2 computes vT = Wv^T * V^T directly (A=wtv, Bt=vin) so the store is
// row-major coalesced like mode 1 (no scattered 2B writes at 4KB stride).
// ---------------------------------------------------------------------------
__global__ __launch_bounds__(256) void proj_all(const __bf16* __restrict__ qin,
                                                const __bf16* __restrict__ kin,
                                                const __bf16* __restrict__ vin,
                                                const __bf16* __restrict__ wtq,
                                                const __bf16* __restrict__ wtk,
                                                const __bf16* __restrict__ wtv,
                                                __bf16* __restrict__ qout,
                                                __bf16* __restrict__ kout,
                                                __bf16* __restrict__ vtout) {
    __shared__ __align__(16) __bf16 As[2][128 * 32];
    __shared__ __align__(16) __bf16 Bs[2][128 * 32];
    int bid = blockIdx.x;
    const __bf16 *A, *Bt;
    int mode, b;
    if (bid < 512)      { A = qin; Bt = wtq; mode = 0; b = bid; }
    else if (bid < 640) { A = kin; Bt = wtk; mode = 1; b = bid - 512; }
    else                { A = wtv; Bt = vin; mode = 2; b = bid - 640; }
    int row0, col0;
    if (mode == 2) { row0 = (b >> 4) * 128; col0 = (b & 15) * 128; }   // 8 x 16
    else           { row0 = (b >> 3) * 128; col0 = (b & 7) * 128; }
    f32x4 acc[4][4] = {};
    gemm128(A, Bt, As[0], As[1], Bs[0], Bs[1], row0, col0, acc);
    int lane = threadIdx.x & 63, wave = threadIdx.x >> 6;
    int r16 = lane & 15, qq = lane >> 4;
    int wr = wave >> 1, wc = wave & 1;
#pragma unroll
    for (int i = 0; i < 4; i++)
#pragma unroll
        for (int j = 0; j < 4; j++)
#pragma unroll
            for (int rr = 0; rr < 4; rr++) {
                int grow = row0 + wr * 64 + i * 16 + qq * 4 + rr;
                int gcol = col0 + wc * 64 + j * 16 + r16;
                __bf16 v = (__bf16)acc[i][j][rr];
                if (mode == 0) {
                    int hh = gcol >> 6, d = gcol & 63;
                    int n = grow >> 11, qr = grow & 2047;
                    qout[((size_t)(n * HEADS + hh) * QLEN + qr) * HD + d] = v;
                } else if (mode == 1) {
                    int hh = gcol >> 6, d = gcol & 63;
                    kout[((size_t)hh * KLEN + grow) * HD + d] = v;
                } else {
                    // grow = h*64+d (embed), gcol = k  ->  vT[h][d][k], coalesced
                    vtout[(size_t)grow * KLEN + gcol] = v;
                }
            }
}

// ---------------------------------------------------------------------------
// attention tile compute, K/V read DIRECTLY from global (L2/L1-resident:
// K+V = 512KB/head; the 4 co-resident blocks/CU share the same head+q-tile).
// Effective operand values identical to the LDS-staged version:
//   K frag: row t*64 + kt2*32 + phi(col), chunk 2c+h
//   V frag: vT row col / col+32, chunk 2c+h
// Mask bias as MFMA C-init from LDS (lgkm — does not disturb vmcnt).
// ---------------------------------------------------------------------------
__device__ __forceinline__ void attn_tile(const __bf16* kt, const __bf16* vt,
                                          const float* mrow, const bf16x8 (&qfrag)[4],
                                          int col, int colp, int h,
                                          f32x16& o0, f32x16& o1, f32x2& rsl) {
    bf16x8 pfrag[4];
#pragma unroll
    for (int kt2 = 0; kt2 < 2; kt2++) {
        const __bf16* kr = kt + (kt2 * 32 + colp) * HD + h * 8;
        // C-init with mask bias: s starts at 0 or -1e30 per row
        union { f32x16 v; f32x4 q[4]; } su;
#pragma unroll
        for (int G = 0; G < 4; G++)
            su.q[G] = *(const f32x4*)&mrow[kt2 * 32 + 16 * (G >> 1) + 8 * h + 4 * (G & 1)];
        f32x16 s = su.v;
        __builtin_amdgcn_s_setprio(1);
#pragma unroll
        for (int c = 0; c < 4; c++) {
            bf16x8 kf = *(const bf16x8*)&kr[c * 16];
            s = __builtin_amdgcn_mfma_f32_32x32x16_bf16(kf, qfrag[c], s, 0, 0, 0);
        }
        __builtin_amdgcn_s_setprio(0);
#pragma unroll
        for (int G = 0; G < 4; G++) {
            int ci = 2 * kt2 + (G >> 1), e0 = (G & 1) * 4;
#pragma unroll
            for (int rr = 0; rr < 4; rr += 2) {
                float p0 = fexp2(s[4 * G + rr]);
                float p1 = fexp2(s[4 * G + rr + 1]);
                f32x2 pp; pp[0] = p0; pp[1] = p1;
                rsl += pp;                       // v_pk_add_f32 candidate
                pfrag[ci][e0 + rr] = (__bf16)p0;
                pfrag[ci][e0 + rr + 1] = (__bf16)p1;
            }
        }
    }
    const __bf16* vr0 = vt + (size_t)col * KLEN + h * 8;
    const __bf16* vr1 = vt + (size_t)(32 + col) * KLEN + h * 8;
    __builtin_amdgcn_s_setprio(1);
#pragma unroll
    for (int c = 0; c < 4; c++) {
        bf16x8 v0 = *(const bf16x8*)&vr0[c * 16];
        bf16x8 v1 = *(const bf16x8*)&vr1[c * 16];
        o0 = __builtin_amdgcn_mfma_f32_32x32x16_bf16(v0, pfrag[c], o0, 0, 0, 0);
        o1 = __builtin_amdgcn_mfma_f32_32x32x16_bf16(v1, pfrag[c], o1, 0, 0, 0);
    }
    __builtin_amdgcn_s_setprio(0);
}

// ---------------------------------------------------------------------------
// fused flash attention v8: 32x32x16 MFMA, K/V direct-from-global (no LDS
// staging, NO barriers in main loop — waves fully independent; TLP hides
// L1/L2 latency). LDS = 8KB (mask only).
// grid = (QLEN/128, HEADS, N), block 256.
// ---------------------------------------------------------------------------
__global__ __launch_bounds__(256, 4) void attn_kernel(const __bf16* __restrict__ qb,
                                                      const __bf16* __restrict__ kb,
                                                      const __bf16* __restrict__ vtb,
                                                      const int* __restrict__ mask,
                                                      float* __restrict__ out) {
    __shared__ __align__(16) float msf[KLEN];

    int tid = threadIdx.x, wave = tid >> 6, lane = tid & 63;
    int col = lane & 31, h = lane >> 5;
    int colp = (col & 0x33) | ((col & 4) << 1) | ((col & 8) >> 1);  // phi (bits 2<->3)
    int q0 = blockIdx.x * 128, hh = blockIdx.y, n = blockIdx.z;
    const __bf16* qg = qb + ((size_t)(n * HEADS + hh) * QLEN + q0 + wave * 32 + col) * HD;
    const __bf16* kg = kb + (size_t)hh * KLEN * HD;
    const __bf16* vg = vtb + (size_t)hh * HD * KLEN;
    const int* mg = mask + n * KLEN;

    // Q^T B-frags straight from global
    bf16x8 qfrag[4];
#pragma unroll
    for (int c = 0; c < 4; c++) qfrag[c] = *(const bf16x8*)&qg[c * 16 + h * 8];

    // mask -> LDS once
    {
        int i8 = tid * 8;
        int4 ma = *(const int4*)&mg[i8];
        int4 mb = *(const int4*)&mg[i8 + 4];
        f32x4 fa, fb;
        fa[0] = ma.x ? 0.f : -1e30f; fa[1] = ma.y ? 0.f : -1e30f;
        fa[2] = ma.z ? 0.f : -1e30f; fa[3] = ma.w ? 0.f : -1e30f;
        fb[0] = mb.x ? 0.f : -1e30f; fb[1] = mb.y ? 0.f : -1e30f;
        fb[2] = mb.z ? 0.f : -1e30f; fb[3] = mb.w ? 0.f : -1e30f;
        *(f32x4*)&msf[i8] = fa;
        *(f32x4*)&msf[i8 + 4] = fb;
    }
    __syncthreads();

    f32x16 o0 = {}, o1 = {};
    f32x2 rsl = {};

    for (int t = 0; t < 32; ++t)
        attn_tile(kg + (size_t)t * 64 * HD, vg + t * 64, &msf[t * 64],
                  qfrag, col, colp, h, o0, o1, rsl);

    // epilogue: lane owns q-col q0+wave*32+col
    float rs = rsl[0] + rsl[1];
    rs += __shfl_xor(rs, 32);
    float inv = 1.0f / rs;
    float* op = out + ((size_t)n * QLEN + q0 + wave * 32 + col) * EMBED + hh * HD;
#pragma unroll
    for (int G = 0; G < 4; G++) {
        float4 t0, t1;
        t0.x = o0[4 * G + 0] * inv; t0.y = o0[4 * G + 1] * inv;
        t0.z = o0[4 * G + 2] * inv; t0.w = o0[4 * G + 3] * inv;
        t1.x = o1[4 * G + 0] * inv; t1.y = o1[4 * G + 1] * inv;
        t1.z = o1[4 * G + 2] * inv; t1.w = o1[4 * G + 3] * inv;
        *(float4*)&op[8 * G + 4 * h] = t0;
        *(float4*)&op[32 + 8 * G + 4 * h] = t1;
    }
}

// ---------------------------------------------------------------------------
extern "C" void kernel_launch(void* const* d_in, const int* in_sizes, int n_in,
                              void* d_out, int out_size, void* d_ws, size_t ws_size,
                              hipStream_t stream) {
    const float* queries = (const float*)d_in[0];
    const float* keys    = (const float*)d_in[1];
    const float* values  = (const float*)d_in[2];
    const int*   mask    = (const int*)d_in[3];
    const float* Wq      = (const float*)d_in[4];
    const float* Wk      = (const float*)d_in[5];
    const float* Wv      = (const float*)d_in[6];
    float* out = (float*)d_out;

    const size_t MiB = 1048576;
    char* ws = (char*)d_ws;
    __bf16* qbf   = (__bf16*)(ws);             // 16 MiB  q   [N][H][Q][64] (pre-scaled)
    __bf16* kbf   = (__bf16*)(ws + 16 * MiB);  //  4 MiB  k   [H][K][64]
    __bf16* vtbf  = (__bf16*)(ws + 20 * MiB);  //  4 MiB  vT  [H][64][K]
    __bf16* wtq   = (__bf16*)(ws + 24 * MiB);  //  1 MiB
    __bf16* wtk   = (__bf16*)(ws + 25 * MiB);
    __bf16* wtv   = (__bf16*)(ws + 26 * MiB);
    __bf16* qin   = (__bf16*)(ws + 27 * MiB);  //  8 MiB
    __bf16* kin   = (__bf16*)(ws + 35 * MiB);  //  2 MiB
    __bf16* vin   = (__bf16*)(ws + 37 * MiB);  //  2 MiB

    prep<<<4608, 256, 0, stream>>>(queries, keys, values, Wq, Wk, Wv,
                                   qin, kin, vin, wtq, wtk, wtv);
    proj_all<<<768, 256, 0, stream>>>(qin, kin, vin, wtq, wtk, wtv, qbf, kbf, vtbf);
    attn_kernel<<<dim3(QLEN / 128, HEADS, NB), 256, 0, stream>>>(qbf, kbf, vtbf, mask, out);
}

// Round 5
// 181.506 us; speedup vs baseline: 1.8965x; 1.8965x over previous
//
#include <hip/hip_runtime.h>

#define NB 4
#define QLEN 2048
#define KLEN 2048
#define QDIM 512
#define EMBED 1024
#define HEADS 16
#define HD 64

typedef __bf16 bf16x8 __attribute__((ext_vector_type(8)));
typedef float f32x2 __attribute__((ext_vector_type(2)));
typedef float f32x4 __attribute__((ext_vector_type(4)));
typedef float f32x16 __attribute__((ext_vector_type(16)));

#define CLOG 0.18033688011112042f   // 0.125 * log2(e), folded into Wq

// guaranteed-cheap exp2
__device__ __forceinline__ float fexp2(float x) {
#if __has_builtin(__builtin_amdgcn_exp2f)
    return __builtin_amdgcn_exp2f(x);
#else
    float r;
    asm("v_exp_f32 %0, %1\n\ts_nop 1" : "=v"(r) : "v"(x));
    return r;
#endif
}

#if __has_builtin(__builtin_amdgcn_sched_barrier)
#define SCHED_FENCE() __builtin_amdgcn_sched_barrier(0)
#else
#define SCHED_FENCE()
#endif

// async global->LDS 16B: dest = wave-uniform base + lane*16
__device__ __forceinline__ void dma16(const void* g, void* l) {
    __builtin_amdgcn_global_load_lds(
        (const __attribute__((address_space(1))) void*)g,
        (__attribute__((address_space(3))) void*)l, 16, 0, 0);
}

// ---------------------------------------------------------------------------
// prep: fused bf16 casts (q,k,v) + W transposes. 1D grid of 4608 blocks x 256.
// ---------------------------------------------------------------------------
__global__ __launch_bounds__(256) void prep(const float* __restrict__ q,
                                            const float* __restrict__ k,
                                            const float* __restrict__ v,
                                            const float* __restrict__ Wq,
                                            const float* __restrict__ Wk,
                                            const float* __restrict__ Wv,
                                            __bf16* __restrict__ qd,
                                            __bf16* __restrict__ kd,
                                            __bf16* __restrict__ vd,
                                            __bf16* __restrict__ WtQ,
                                            __bf16* __restrict__ WtK,
                                            __bf16* __restrict__ WtV) {
    __shared__ float tile[32][33];
    int b = blockIdx.x, tid = threadIdx.x;
    if (b < 3072) {
        const float* src; __bf16* dst; int cb;
        if (b < 2048)      { src = q; dst = qd; cb = b; }
        else if (b < 2560) { src = k; dst = kd; cb = b - 2048; }
        else               { src = v; dst = vd; cb = b - 2560; }
        int i = (cb * 256 + tid) * 8;
        float4 a0 = *(const float4*)&src[i];
        float4 a1 = *(const float4*)&src[i + 4];
        bf16x8 o;
        o[0] = (__bf16)a0.x; o[1] = (__bf16)a0.y; o[2] = (__bf16)a0.z; o[3] = (__bf16)a0.w;
        o[4] = (__bf16)a1.x; o[5] = (__bf16)a1.y; o[6] = (__bf16)a1.z; o[7] = (__bf16)a1.w;
        *(bf16x8*)&dst[i] = o;
    } else {
        int tb = b - 3072;
        int which = tb >> 9, r = tb & 511;
        const float* src = (which == 0) ? Wq : (which == 1) ? Wk : Wv;
        __bf16* dst = (which == 0) ? WtQ : (which == 1) ? WtK : WtV;
        float scale = (which == 0) ? CLOG : 1.0f;
        int e0 = (r & 31) * 32, c0 = (r >> 5) * 32;
        int tx = tid & 31, ty = tid >> 5;  // 32 x 8
        for (int i = 0; i < 4; i++)
            tile[ty + 8 * i][tx] = src[(c0 + ty + 8 * i) * EMBED + e0 + tx];
        __syncthreads();
        for (int i = 0; i < 4; i++)
            dst[(e0 + ty + 8 * i) * QDIM + c0 + tx] = (__bf16)(tile[tx][ty + 8 * i] * scale);
    }
}

// ---------------------------------------------------------------------------
// 128x128-tile GEMM body, double-buffered DMA staging, BK=32, 2x2 wave grid
// ---------------------------------------------------------------------------
__device__ __forceinline__ void gemm_compute(const __bf16* As, const __bf16* Bs,
                                             int wr, int wc, int r16, int qq,
                                             f32x4 (&acc)[4][4]) {
    bf16x8 af[4], bq[4];
#pragma unroll
    for (int i = 0; i < 4; i++)
        af[i] = *(const bf16x8*)&As[(wr * 64 + i * 16 + r16) * 32 + qq * 8];
#pragma unroll
    for (int j = 0; j < 4; j++)
        bq[j] = *(const bf16x8*)&Bs[(wc * 64 + j * 16 + r16) * 32 + qq * 8];
#pragma unroll
    for (int i = 0; i < 4; i++)
#pragma unroll
        for (int j = 0; j < 4; j++)
            acc[i][j] = __builtin_amdgcn_mfma_f32_16x16x32_bf16(af[i], bq[j], acc[i][j], 0, 0, 0);
}

__device__ __forceinline__ void gemm128(const __bf16* __restrict__ A,
                                        const __bf16* __restrict__ Bt,
                                        __bf16* As0, __bf16* As1,
                                        __bf16* Bs0, __bf16* Bs1,
                                        int row0, int col0, f32x4 (&acc)[4][4]) {
    int tid = threadIdx.x, wave = tid >> 6, lane = tid & 63;
    int r16 = lane & 15, qq = lane >> 4;
    int wr = wave >> 1, wc = wave & 1;
    const __bf16* agp1 = A + (size_t)(row0 + (tid >> 2)) * QDIM + (tid & 3) * 8;
    const __bf16* agp2 = A + (size_t)(row0 + 64 + (tid >> 2)) * QDIM + (tid & 3) * 8;
    const __bf16* bgp1 = Bt + (size_t)(col0 + (tid >> 2)) * QDIM + (tid & 3) * 8;
    const __bf16* bgp2 = Bt + (size_t)(col0 + 64 + (tid >> 2)) * QDIM + (tid & 3) * 8;
    __bf16 *a0a = &As0[wave * 512], *a0b = &As0[2048 + wave * 512];
    __bf16 *a1a = &As1[wave * 512], *a1b = &As1[2048 + wave * 512];
    __bf16 *b0a = &Bs0[wave * 512], *b0b = &Bs0[2048 + wave * 512];
    __bf16 *b1a = &Bs1[wave * 512], *b1b = &Bs1[2048 + wave * 512];

    // prologue: tile 0 -> buf0
    dma16(agp1, a0a); dma16(agp2, a0b);
    dma16(bgp1, b0a); dma16(bgp2, b0b);
    agp1 += 32; agp2 += 32; bgp1 += 32; bgp2 += 32;
    __syncthreads();

    for (int t = 0; t < 16; t += 2) {
        // prefetch tile t+1 -> buf1 (t+1 <= 15 always)
        dma16(agp1, a1a); dma16(agp2, a1b);
        dma16(bgp1, b1a); dma16(bgp2, b1b);
        agp1 += 32; agp2 += 32; bgp1 += 32; bgp2 += 32;
        SCHED_FENCE();
        gemm_compute(As0, Bs0, wr, wc, r16, qq, acc);
        __syncthreads();
        if (t + 2 < 16) {
            dma16(agp1, a0a); dma16(agp2, a0b);
            dma16(bgp1, b0a); dma16(bgp2, b0b);
            agp1 += 32; agp2 += 32; bgp1 += 32; bgp2 += 32;
        }
        SCHED_FENCE();
        gemm_compute(As1, Bs1, wr, wc, r16, qq, acc);
        __syncthreads();
    }
}

// ---------------------------------------------------------------------------
// fused projections: bid<512 -> q ; <640 -> k ; else -> vT
// mode 2 computes vT = Wv^T * V^T directly (A=wtv, Bt=vin) so the store is
// row-major coalesced like mode 1 (no scattered 2B writes at 4KB stride).
// ---------------------------------------------------------------------------
__global__ __launch_bounds__(256) void proj_all(const __bf16* __restrict__ qin,
                                                const __bf16* __restrict__ kin,
                                                const __bf16* __restrict__ vin,
                                                const __bf16* __restrict__ wtq,
                                                const __bf16* __restrict__ wtk,
                                                const __bf16* __restrict__ wtv,
                                                __bf16* __restrict__ qout,
                                                __bf16* __restrict__ kout,
                                                __bf16* __restrict__ vtout) {
    __shared__ __align__(16) __bf16 As[2][128 * 32];
    __shared__ __align__(16) __bf16 Bs[2][128 * 32];
    int bid = blockIdx.x;
    const __bf16 *A, *Bt;
    int mode, b;
    if (bid < 512)      { A = qin; Bt = wtq; mode = 0; b = bid; }
    else if (bid < 640) { A = kin; Bt = wtk; mode = 1; b = bid - 512; }
    else                { A = wtv; Bt = vin; mode = 2; b = bid - 640; }
    int row0, col0;
    if (mode == 2) { row0 = (b >> 4) * 128; col0 = (b & 15) * 128; }   // 8 x 16
    else           { row0 = (b >> 3) * 128; col0 = (b & 7) * 128; }
    f32x4 acc[4][4] = {};
    gemm128(A, Bt, As[0], As[1], Bs[0], Bs[1], row0, col0, acc);
    int lane = threadIdx.x & 63, wave = threadIdx.x >> 6;
    int r16 = lane & 15, qq = lane >> 4;
    int wr = wave >> 1, wc = wave & 1;
#pragma unroll
    for (int i = 0; i < 4; i++)
#pragma unroll
        for (int j = 0; j < 4; j++)
#pragma unroll
            for (int rr = 0; rr < 4; rr++) {
                int grow = row0 + wr * 64 + i * 16 + qq * 4 + rr;
                int gcol = col0 + wc * 64 + j * 16 + r16;
                __bf16 v = (__bf16)acc[i][j][rr];
                if (mode == 0) {
                    int hh = gcol >> 6, d = gcol & 63;
                    int n = grow >> 11, qr = grow & 2047;
                    qout[((size_t)(n * HEADS + hh) * QLEN + qr) * HD + d] = v;
                } else if (mode == 1) {
                    int hh = gcol >> 6, d = gcol & 63;
                    kout[((size_t)hh * KLEN + grow) * HD + d] = v;
                } else {
                    // grow = h*64+d (embed), gcol = k  ->  vT[h][d][k], coalesced
                    vtout[(size_t)grow * KLEN + gcol] = v;
                }
            }
}

// ---------------------------------------------------------------------------
// attention tile compute: mask bias as MFMA C-init from LDS, paired row-sum
// accumulate, setprio on MFMA clusters (T5). Round-2 verified core.
// ---------------------------------------------------------------------------
__device__ __forceinline__ void attn_tile(const __bf16* ksb, const __bf16* vsb,
                                          const float* mrow, const bf16x8 (&qfrag)[4],
                                          int col, int h,
                                          f32x16& o0, f32x16& o1, f32x2& rsl) {
    bf16x8 pfrag[4];
#pragma unroll
    for (int kt2 = 0; kt2 < 2; kt2++) {
        int R = kt2 * 32 + col;
        // C-init with mask bias: s starts at 0 or -1e30 per row
        union { f32x16 v; f32x4 q[4]; } su;
#pragma unroll
        for (int G = 0; G < 4; G++)
            su.q[G] = *(const f32x4*)&mrow[kt2 * 32 + 16 * (G >> 1) + 8 * h + 4 * (G & 1)];
        f32x16 s = su.v;
        __builtin_amdgcn_s_setprio(1);
#pragma unroll
        for (int c = 0; c < 4; c++) {
            int cc = (2 * c + h) ^ (R & 7);
            bf16x8 kf = *(const bf16x8*)&ksb[(R * 8 + cc) * 8];
            s = __builtin_amdgcn_mfma_f32_32x32x16_bf16(kf, qfrag[c], s, 0, 0, 0);
        }
        __builtin_amdgcn_s_setprio(0);
#pragma unroll
        for (int G = 0; G < 4; G++) {
            int ci = 2 * kt2 + (G >> 1), e0 = (G & 1) * 4;
#pragma unroll
            for (int rr = 0; rr < 4; rr += 2) {
                float p0 = fexp2(s[4 * G + rr]);
                float p1 = fexp2(s[4 * G + rr + 1]);
                f32x2 pp; pp[0] = p0; pp[1] = p1;
                rsl += pp;                       // v_pk_add_f32 candidate
                pfrag[ci][e0 + rr] = (__bf16)p0;
                pfrag[ci][e0 + rr + 1] = (__bf16)p1;
            }
        }
    }
    __builtin_amdgcn_s_setprio(1);
#pragma unroll
    for (int c = 0; c < 4; c++) {
        int cc = (2 * c + h) ^ (col & 7);
        bf16x8 v0 = *(const bf16x8*)&vsb[(col * 8 + cc) * 8];
        bf16x8 v1 = *(const bf16x8*)&vsb[((32 + col) * 8 + cc) * 8];
        o0 = __builtin_amdgcn_mfma_f32_32x32x16_bf16(v0, pfrag[c], o0, 0, 0, 0);
        o1 = __builtin_amdgcn_mfma_f32_32x32x16_bf16(v1, pfrag[c], o1, 0, 0, 0);
    }
    __builtin_amdgcn_s_setprio(0);
}

// ---------------------------------------------------------------------------
// fused flash attention v9: 512-thread blocks (8 waves, 256 q-rows/block).
// grid = 512 blocks = exactly 2/CU; LDS 2x40KB = 80KB guaranteed resident
// (round-2's 4x40KB = 160KB exactly was residency-capped at ~3 blocks).
// Staging: 1 dma16/thread/array per tile (tid>>3 spans all 64 rows; same
// phi/XOR source swizzle, linear LDS dest). Double-buffered, 1 barrier/tile.
// grid = (QLEN/256, HEADS, N), block 512.
// ---------------------------------------------------------------------------
__global__ __launch_bounds__(512, 4) void attn_kernel(const __bf16* __restrict__ qb,
                                                      const __bf16* __restrict__ kb,
                                                      const __bf16* __restrict__ vtb,
                                                      const int* __restrict__ mask,
                                                      float* __restrict__ out) {
    __shared__ __align__(16) __bf16 ks[2][4096];
    __shared__ __align__(16) __bf16 vs[2][4096];
    __shared__ __align__(16) float msf[KLEN];

    int tid = threadIdx.x, wave = tid >> 6, lane = tid & 63;
    int col = lane & 31, h = lane >> 5;
    int q0 = blockIdx.x * 256, hh = blockIdx.y, n = blockIdx.z;
    const __bf16* qg = qb + ((size_t)(n * HEADS + hh) * QLEN + q0 + wave * 32 + col) * HD;
    const __bf16* kg = kb + (size_t)hh * KLEN * HD;
    const __bf16* vg = vtb + (size_t)hh * HD * KLEN;
    const int* mg = mask + n * KLEN;

    // Q^T B-frags straight from global
    bf16x8 qfrag[4];
#pragma unroll
    for (int c = 0; c < 4; c++) qfrag[c] = *(const bf16x8*)&qg[c * 16 + h * 8];

    // DMA slot assignment (phi on k rows, XOR chunk swizzle); tid 0..511 spans
    // the full 64-row tile: R1 = tid>>3, one dma16 per array per tile.
    int R1 = tid >> 3, c1 = (tid & 7) ^ (R1 & 7);
    int g1 = (R1 & 0x33) | ((R1 & 4) << 1) | ((R1 & 8) >> 1);
    const __bf16* kgp1 = kg + g1 * HD + c1 * 8;
    const __bf16* vgp1 = vg + (size_t)R1 * KLEN + c1 * 8;
    __bf16 *kl0 = &ks[0][wave * 512], *kl1 = &ks[1][wave * 512];
    __bf16 *vl0 = &vs[0][wave * 512], *vl1 = &vs[1][wave * 512];

    // prologue: DMA tile 0 -> buf0, and mask -> LDS once (512 thr x 4 ints)
    dma16(kgp1, kl0); dma16(vgp1, vl0);
    kgp1 += 64 * HD; vgp1 += 64;
    {
        int i4 = tid * 4;
        int4 ma = *(const int4*)&mg[i4];
        f32x4 fa;
        fa[0] = ma.x ? 0.f : -1e30f; fa[1] = ma.y ? 0.f : -1e30f;
        fa[2] = ma.z ? 0.f : -1e30f; fa[3] = ma.w ? 0.f : -1e30f;
        *(f32x4*)&msf[i4] = fa;
    }
    __syncthreads();

    f32x16 o0 = {}, o1 = {};
    f32x2 rsl = {};

    for (int t = 0; t < 32; t += 2) {
        // prefetch tile t+1 -> buf1 (t+1 <= 31 always valid)
        dma16(kgp1, kl1); dma16(vgp1, vl1);
        kgp1 += 64 * HD; vgp1 += 64;
        SCHED_FENCE();
        attn_tile(ks[0], vs[0], &msf[t * 64], qfrag, col, h, o0, o1, rsl);
        __syncthreads();   // drains buf1 DMA (covered by compute above)
        if (t + 2 < 32) {
            dma16(kgp1, kl0); dma16(vgp1, vl0);
            kgp1 += 64 * HD; vgp1 += 64;
        }
        SCHED_FENCE();
        attn_tile(ks[1], vs[1], &msf[(t + 1) * 64], qfrag, col, h, o0, o1, rsl);
        __syncthreads();
    }

    // epilogue: lane owns q-col q0+wave*32+col
    float rs = rsl[0] + rsl[1];
    rs += __shfl_xor(rs, 32);
    float inv = 1.0f / rs;
    float* op = out + ((size_t)n * QLEN + q0 + wave * 32 + col) * EMBED + hh * HD;
#pragma unroll
    for (int G = 0; G < 4; G++) {
        float4 t0, t1;
        t0.x = o0[4 * G + 0] * inv; t0.y = o0[4 * G + 1] * inv;
        t0.z = o0[4 * G + 2] * inv; t0.w = o0[4 * G + 3] * inv;
        t1.x = o1[4 * G + 0] * inv; t1.y = o1[4 * G + 1] * inv;
        t1.z = o1[4 * G + 2] * inv; t1.w = o1[4 * G + 3] * inv;
        *(float4*)&op[8 * G + 4 * h] = t0;
        *(float4*)&op[32 + 8 * G + 4 * h] = t1;
    }
}

// ---------------------------------------------------------------------------
extern "C" void kernel_launch(void* const* d_in, const int* in_sizes, int n_in,
                              void* d_out, int out_size, void* d_ws, size_t ws_size,
                              hipStream_t stream) {
    const float* queries = (const float*)d_in[0];
    const float* keys    = (const float*)d_in[1];
    const float* values  = (const float*)d_in[2];
    const int*   mask    = (const int*)d_in[3];
    const float* Wq      = (const float*)d_in[4];
    const float* Wk      = (const float*)d_in[5];
    const float* Wv      = (const float*)d_in[6];
    float* out = (float*)d_out;

    const size_t MiB = 1048576;
    char* ws = (char*)d_ws;
    __bf16* qbf   = (__bf16*)(ws);             // 16 MiB  q   [N][H][Q][64] (pre-scaled)
    __bf16* kbf   = (__bf16*)(ws + 16 * MiB);  //  4 MiB  k   [H][K][64]
    __bf16* vtbf  = (__bf16*)(ws + 20 * MiB);  //  4 MiB  vT  [H][64][K]
    __bf16* wtq   = (__bf16*)(ws + 24 * MiB);  //  1 MiB
    __bf16* wtk   = (__bf16*)(ws + 25 * MiB);
    __bf16* wtv   = (__bf16*)(ws + 26 * MiB);
    __bf16* qin   = (__bf16*)(ws + 27 * MiB);  //  8 MiB
    __bf16* kin   = (__bf16*)(ws + 35 * MiB);  //  2 MiB
    __bf16* vin   = (__bf16*)(ws + 37 * MiB);  //  2 MiB

    prep<<<4608, 256, 0, stream>>>(queries, keys, values, Wq, Wk, Wv,
                                   qin, kin, vin, wtq, wtk, wtv);
    proj_all<<<768, 256, 0, stream>>>(qin, kin, vin, wtq, wtk, wtv, qbf, kbf, vtbf);
    attn_kernel<<<dim3(QLEN / 256, HEADS, NB), 512, 0, stream>>>(qbf, kbf, vtbf, mask, out);
}